// Round 1
// baseline (303.263 us; speedup 1.0000x reference)
//
#include <hip/hip_runtime.h>
#include <hip/hip_bf16.h>
#include <stdint.h>
#include <stddef.h>

// E=8, B=16, T=512, DIN=256, D=256; M = B*T = 8192 rows per ensemble member.
// Stage1: u = x @ W_in[m]  (per e), v=tanh(u0), f=sig(u1)*(1-rs)  -> scan1 -> v4
// Stage2: u = v4 @ W_mid[m], f,i,o,z                               -> scan2 -> g = h*o
// Stage3: out = g @ W_out + b_out
//
// All GEMMs in bf16 MFMA (16x16x32), f32 accum. Scans keep h in f32.

typedef __bf16 bf16x8 __attribute__((ext_vector_type(8)));
typedef __bf16 bf16x4 __attribute__((ext_vector_type(4)));
typedef __bf16 bf16x2 __attribute__((ext_vector_type(2)));
typedef float  f32x4  __attribute__((ext_vector_type(4)));

#define E_ 8
#define M_ 8192
#define K_ 256
#define D_ 256

__device__ __forceinline__ float sigm_f(float x) { return 1.0f / (1.0f + __expf(-x)); }
__device__ __forceinline__ float tanh_f(float x) { return 1.0f - 2.0f / (1.0f + __expf(2.0f * x)); }

__device__ __forceinline__ void g2lds16(const void* g, void* l) {
    __builtin_amdgcn_global_load_lds((const __attribute__((address_space(1))) void*)g,
                                     (__attribute__((address_space(3))) void*)l, 16, 0, 0);
}

// ---------------- convert x to bf16 ----------------
__global__ __launch_bounds__(256) void convx_k(const float* __restrict__ x, __bf16* __restrict__ xb) {
    int i = blockIdx.x * 256 + threadIdx.x;           // handles 4 elems
    float4 v = ((const float4*)x)[i];
    bf16x4 o;
    o[0] = (__bf16)v.x; o[1] = (__bf16)v.y; o[2] = (__bf16)v.z; o[3] = (__bf16)v.w;
    ((bf16x4*)xb)[i] = o;
}

// ---------------- transpose+convert weights: src [GE][K][D] f32 -> dst [E][NG*256][K] bf16 ----
// dst row index = g*256 + d (for ensemble e); ge = g*E + e.
__global__ __launch_bounds__(256) void transw_k(const float* __restrict__ src, __bf16* __restrict__ dst, int NG) {
    int ge = blockIdx.z;
    int g = ge >> 3, e = ge & 7;
    int k0 = blockIdx.x * 64, d0 = blockIdx.y * 64;
    __shared__ float tile[64][65];
    int t = threadIdx.x;
#pragma unroll
    for (int j = 0; j < 16; ++j) {
        int lin = j * 256 + t;
        int r = lin >> 6, c = lin & 63;           // r = k offset, c = d offset
        tile[r][c] = src[((size_t)(ge * 256 + k0 + r)) * 256 + d0 + c];
    }
    __syncthreads();
#pragma unroll
    for (int j = 0; j < 16; ++j) {
        int lin = j * 256 + t;
        int r = lin >> 6, c = lin & 63;           // r = d offset, c = k offset
        dst[((size_t)((e * NG + g) * 256 + d0 + r)) * 256 + k0 + c] = (__bf16)tile[c][r];
    }
}

// ---------------- GEMM: A [E][M][K] bf16 x Wt [E][NG*256][K] bf16 -----------
// MODE 0: stage1 (NG=2: g0 tanh -> V, g1 sigmoid*(1-rs) -> F), bf16 out slabs [NG][E][M][D]
// MODE 1: stage2 (NG=4: g0 sig*(1-rs), g1 sig, g2 sig, g3 tanh)
// MODE 2: stage3 (NG=1: linear + bias, f32 out to d_out)
template <int MODE, int NG>
__global__ __launch_bounds__(256) void gemm_k(const __bf16* __restrict__ A,
                                              const __bf16* __restrict__ Wt,
                                              const float* __restrict__ bias,
                                              const float* __restrict__ rs,
                                              __bf16* __restrict__ gout,
                                              float* __restrict__ fout) {
    const int tid = threadIdx.x;
    const int nt = blockIdx.x, mt = blockIdx.y, e = blockIdx.z;
    const int m0 = mt * 128;
    const int lane = tid & 63, wid = tid >> 6;
    const int wr = wid >> 1, wc = wid & 1;

    __shared__ __align__(16) __bf16 As[128 * 64];   // [row][64] with XOR-swizzled 16B granules
    __shared__ __align__(16) __bf16 Bs[128 * 64];   // [col][64] (Wt rows = output cols)

    const size_t Abase = ((size_t)e * M_ + m0) * K_;
    const size_t Bbase = ((size_t)e * (NG * 256) + nt * 128) * K_;

    f32x4 acc[4][4] = {};

    for (int kt = 0; kt < 4; ++kt) {
        __syncthreads();
        // stage A and B tiles; LDS dest linear, global source pre-swizzled (granule g ^= row&7)
#pragma unroll
        for (int r = 0; r < 4; ++r) {
            int P = r * 256 + tid;                  // 16B-granule index, 0..1023
            int row = P >> 3, gl = P & 7;
            int gs = gl ^ (row & 7);
            g2lds16(A + Abase + (size_t)row * K_ + kt * 64 + gs * 8, &As[P * 8]);
            g2lds16(Wt + Bbase + (size_t)row * K_ + kt * 64 + gs * 8, &Bs[P * 8]);
        }
        __syncthreads();
#pragma unroll
        for (int ks = 0; ks < 2; ++ks) {
            bf16x8 af[4], bf[4];
#pragma unroll
            for (int i = 0; i < 4; ++i) {
                int ar = wr * 64 + i * 16 + (lane & 15);
                int ag = (ks * 4 + (lane >> 4)) ^ (ar & 7);
                af[i] = *(const bf16x8*)&As[ar * 64 + ag * 8];
                int bc = wc * 64 + i * 16 + (lane & 15);
                int bg = (ks * 4 + (lane >> 4)) ^ (bc & 7);
                bf[i] = *(const bf16x8*)&Bs[bc * 64 + bg * 8];
            }
#pragma unroll
            for (int i = 0; i < 4; ++i)
#pragma unroll
                for (int j = 0; j < 4; ++j)
                    acc[i][j] = __builtin_amdgcn_mfma_f32_16x16x32_bf16(af[i], bf[j], acc[i][j], 0, 0, 0);
        }
    }

    // epilogue: C row = (lane>>4)*4 + q, col = lane&15 within each 16x16 fragment
#pragma unroll
    for (int i = 0; i < 4; ++i) {
#pragma unroll
        for (int j = 0; j < 4; ++j) {
            int gcol = nt * 128 + wc * 64 + j * 16 + (lane & 15);
            int g = gcol >> 8, d = gcol & 255;
            float bv = bias[(g * E_ + e) * 256 + d];
#pragma unroll
            for (int q = 0; q < 4; ++q) {
                int grow = m0 + wr * 64 + i * 16 + ((lane >> 4) << 2) + q;
                float u = acc[i][j][q] + bv;
                if (MODE == 2) {
                    fout[((size_t)e * M_ + grow) * 256 + d] = u;
                } else {
                    bool is_tanh = (MODE == 0) ? (g == 0) : (g == 3);
                    bool gated   = (MODE == 0) ? (g == 1) : (g == 0);
                    float act = is_tanh ? tanh_f(u) : sigm_f(u);
                    if (gated) act *= (1.0f - rs[grow]);
                    gout[(((size_t)g * E_ + e) * M_ + grow) * 256 + d] = (__bf16)act;
                }
            }
        }
    }
}

// ---------------- scan 1: h = f*h + (1-f)*v, write v4 (bf16) + h_last -> hidden_out[:,0:256]
__global__ __launch_bounds__(64) void scan1_k(const __bf16* __restrict__ V, const __bf16* __restrict__ F,
                                              const float* __restrict__ hidden,
                                              __bf16* __restrict__ v4b, float* __restrict__ hidout) {
    int gid = blockIdx.x * 64 + threadIdx.x;     // 0..16383
    int n = gid >> 7, dp = gid & 127;
    int d0 = dp * 2;
    float h0 = hidden[n * 512 + d0];
    float h1 = hidden[n * 512 + d0 + 1];
    size_t base = ((size_t)n * 512) * 256 + d0;
    for (int tb = 0; tb < 512; tb += 16) {
        bf16x2 vv[16], ff[16];
#pragma unroll
        for (int u = 0; u < 16; ++u) {
            size_t idx = base + (size_t)(tb + u) * 256;
            vv[u] = *(const bf16x2*)&V[idx];
            ff[u] = *(const bf16x2*)&F[idx];
        }
#pragma unroll
        for (int u = 0; u < 16; ++u) {
            float f0 = (float)ff[u][0], f1 = (float)ff[u][1];
            float v0 = (float)vv[u][0], v1 = (float)vv[u][1];
            h0 = f0 * h0 + (1.0f - f0) * v0;
            h1 = f1 * h1 + (1.0f - f1) * v1;
            bf16x2 o; o[0] = (__bf16)h0; o[1] = (__bf16)h1;
            size_t idx = base + (size_t)(tb + u) * 256;
            *(bf16x2*)&v4b[idx] = o;
        }
    }
    hidout[n * 512 + d0] = h0;
    hidout[n * 512 + d0 + 1] = h1;
}

// ---------------- scan 2: h = f*h + (1-f)*(i*z); out = h*o (bf16) + h_last -> hidden_out[:,256:512]
__global__ __launch_bounds__(64) void scan2_k(const __bf16* __restrict__ Fg, const __bf16* __restrict__ Ig,
                                              const __bf16* __restrict__ Og, const __bf16* __restrict__ Zg,
                                              const float* __restrict__ hidden,
                                              __bf16* __restrict__ G, float* __restrict__ hidout) {
    int gid = blockIdx.x * 64 + threadIdx.x;
    int n = gid >> 7, dp = gid & 127;
    int d0 = dp * 2;
    float h0 = hidden[n * 512 + 256 + d0];
    float h1 = hidden[n * 512 + 256 + d0 + 1];
    size_t base = ((size_t)n * 512) * 256 + d0;
    for (int tb = 0; tb < 512; tb += 8) {
        bf16x2 ff[8], ii[8], oo[8], zz[8];
#pragma unroll
        for (int u = 0; u < 8; ++u) {
            size_t idx = base + (size_t)(tb + u) * 256;
            ff[u] = *(const bf16x2*)&Fg[idx];
            ii[u] = *(const bf16x2*)&Ig[idx];
            oo[u] = *(const bf16x2*)&Og[idx];
            zz[u] = *(const bf16x2*)&Zg[idx];
        }
#pragma unroll
        for (int u = 0; u < 8; ++u) {
            float f0 = (float)ff[u][0], f1 = (float)ff[u][1];
            float i0 = (float)ii[u][0], i1 = (float)ii[u][1];
            float o0 = (float)oo[u][0], o1 = (float)oo[u][1];
            float z0 = (float)zz[u][0], z1 = (float)zz[u][1];
            h0 = f0 * h0 + (1.0f - f0) * (i0 * z0);
            h1 = f1 * h1 + (1.0f - f1) * (i1 * z1);
            bf16x2 og; og[0] = (__bf16)(h0 * o0); og[1] = (__bf16)(h1 * o1);
            size_t idx = base + (size_t)(tb + u) * 256;
            *(bf16x2*)&G[idx] = og;
        }
    }
    hidout[n * 512 + 256 + d0] = h0;
    hidout[n * 512 + 256 + d0 + 1] = h1;
}

extern "C" void kernel_launch(void* const* d_in, const int* in_sizes, int n_in,
                              void* d_out, int out_size, void* d_ws, size_t ws_size,
                              hipStream_t stream) {
    const float* x      = (const float*)d_in[0];   // [8,16,512,256]
    const float* hidden = (const float*)d_in[1];   // [1,128,512]
    const float* rs     = (const float*)d_in[2];   // [16,512,1] -> flat [8192]
    const float* W_in   = (const float*)d_in[3];   // [2,8,256,256]
    const float* b_in   = (const float*)d_in[4];   // [2,8,256]
    const float* W_mid  = (const float*)d_in[5];   // [4,8,256,256]
    const float* b_mid  = (const float*)d_in[6];   // [4,8,256]
    const float* W_out  = (const float*)d_in[7];   // [8,256,256]
    const float* b_out  = (const float*)d_in[8];   // [8,256]
    float* out = (float*)d_out;                    // [8,16,512,256] + [1,128,512]

    char* ws = (char*)d_ws;
    const size_t MiB = (size_t)1 << 20;
    __bf16* Wt1 = (__bf16*)(ws + 0);               // 2 MiB   [8][512][256]
    __bf16* Wt2 = (__bf16*)(ws + 2 * MiB);         // 4 MiB   [8][1024][256]
    __bf16* Wt3 = (__bf16*)(ws + 6 * MiB);         // 1 MiB   [8][256][256]
    __bf16* v4b = (__bf16*)(ws + 8 * MiB);         // 32 MiB  [E][M][D] ; reused as G after gemm2
    __bf16* xb  = (__bf16*)(ws + 40 * MiB);        // 32 MiB
    __bf16* g1  = (__bf16*)(ws + 72 * MiB);        // 64 MiB  [2][E][M][D]
    __bf16* g2  = (__bf16*)(ws + 40 * MiB);        // 128 MiB [4][E][M][D], overlays xb+g1+extra
    const size_t S1 = (size_t)E_ * M_ * D_;        // 16,777,216 elems per gate slab

    float* hidout = out + (size_t)E_ * M_ * D_;    // second output: [1,128,512]

    // 1) dtype conversions / weight transposes
    convx_k<<<16384, 256, 0, stream>>>(x, xb);
    transw_k<<<dim3(4, 4, 16), 256, 0, stream>>>(W_in, Wt1, 2);
    transw_k<<<dim3(4, 4, 32), 256, 0, stream>>>(W_mid, Wt2, 4);
    transw_k<<<dim3(4, 4, 8), 256, 0, stream>>>(W_out, Wt3, 1);

    // 2) stage 1 GEMM + activations
    gemm_k<0, 2><<<dim3(4, 64, 8), 256, 0, stream>>>(xb, Wt1, b_in, rs, g1, nullptr);
    // 3) scan 1
    scan1_k<<<256, 64, 0, stream>>>(g1, g1 + S1, hidden, v4b, hidout);
    // 4) stage 2 GEMM + activations
    gemm_k<1, 4><<<dim3(8, 64, 8), 256, 0, stream>>>(v4b, Wt2, b_mid, rs, g2, nullptr);
    // 5) scan 2 (writes G into v4b region; gemm2 consumers already done)
    scan2_k<<<256, 64, 0, stream>>>(g2, g2 + S1, g2 + 2 * S1, g2 + 3 * S1, hidden, v4b, hidout);
    // 6) output projection -> d_out
    gemm_k<2, 1><<<dim3(2, 64, 8), 256, 0, stream>>>(v4b, Wt3, b_out, nullptr, nullptr, out);
}